// Round 1
// baseline (1365.546 us; speedup 1.0000x reference)
//
#include <hip/hip_runtime.h>

// Sinkhorn over [B=256, N=512, N=512] fp32, 10 iterations.
//
// Log-space Sinkhorn == linear-space Sinkhorn with potentials:
//   K = exp(la0); repeat { u_i = 1/sum_j K_ij v_j ; v_j = 1/sum_i K_ij u_i }
//   out_ij = K_ij * u_i * v_j
// K stays register-resident for the whole kernel: one block per matrix,
// 1024 threads, 256 floats (64 x float4) per thread, all statically indexed.

constexpr int N      = 512;
constexpr int WAVES  = 16;   // 1024 threads
constexpr int RPW    = 32;   // rows per wave = 512/16
constexpr int NITER  = 10;

__global__ __launch_bounds__(1024, 4)
void sinkhorn_kernel(const float* __restrict__ in, float* __restrict__ out)
{
    const int tid = threadIdx.x;
    const int w   = tid >> 6;   // wave id 0..15
    const int l   = tid & 63;   // lane

    __shared__ float part[WAVES][N];  // 32 KB: per-wave column partial sums
    __shared__ float vres[N];         // 2 KB: broadcast v_j

    const size_t mat = (size_t)blockIdx.x * N * N;
    const float* A = in  + mat;
    float*       O = out + mat;

    const int row0 = w * RPW;
    const int col  = l * 4;   // lane's base column within each 256-wide half

    // K values: a[r][k] = K[row0+r][k*256 + col .. +3]
    float4 a[RPW][2];

    #pragma unroll
    for (int r = 0; r < RPW; ++r) {
        #pragma unroll
        for (int k = 0; k < 2; ++k) {
            float4 t = *reinterpret_cast<const float4*>(
                A + (size_t)(row0 + r) * N + k * 256 + col);
            a[r][k] = make_float4(__expf(t.x), __expf(t.y),
                                  __expf(t.z), __expf(t.w));
        }
    }

    float4 v0 = make_float4(1.f, 1.f, 1.f, 1.f);  // v for cols [col..col+3]
    float4 v1 = v0;                               // v for cols [256+col..]
    float  u[RPW];

    for (int it = 0; it < NITER; ++it) {
        // ---- row pass: u_r = 1 / sum_j K_rj * v_j ----
        #pragma unroll
        for (int r = 0; r < RPW; ++r) {
            float p = a[r][0].x * v0.x + a[r][0].y * v0.y
                    + a[r][0].z * v0.z + a[r][0].w * v0.w
                    + a[r][1].x * v1.x + a[r][1].y * v1.y
                    + a[r][1].z * v1.z + a[r][1].w * v1.w;
            // full-wave butterfly: every lane ends with the row total
            #pragma unroll
            for (int d = 1; d < 64; d <<= 1)
                p += __shfl_xor(p, d, 64);
            u[r] = 1.0f / p;
        }

        // ---- col partials over this wave's 32 rows ----
        float4 t0 = make_float4(0.f, 0.f, 0.f, 0.f);
        float4 t1 = make_float4(0.f, 0.f, 0.f, 0.f);
        #pragma unroll
        for (int r = 0; r < RPW; ++r) {
            const float ur = u[r];
            t0.x += a[r][0].x * ur; t0.y += a[r][0].y * ur;
            t0.z += a[r][0].z * ur; t0.w += a[r][0].w * ur;
            t1.x += a[r][1].x * ur; t1.y += a[r][1].y * ur;
            t1.z += a[r][1].z * ur; t1.w += a[r][1].w * ur;
        }
        *reinterpret_cast<float4*>(&part[w][col])       = t0;
        *reinterpret_cast<float4*>(&part[w][256 + col]) = t1;
        __syncthreads();

        // ---- cross-wave column reduce: 2 threads per column ----
        {
            const int j  = tid >> 1;   // column 0..511
            const int pp = tid & 1;    // which 8 waves
            float s = 0.f;
            #pragma unroll
            for (int ww = 0; ww < 8; ++ww)
                s += part[pp * 8 + ww][j];
            s += __shfl_xor(s, 1, 64);
            if (pp == 0) vres[j] = 1.0f / s;
        }
        __syncthreads();

        v0 = *reinterpret_cast<const float4*>(&vres[col]);
        v1 = *reinterpret_cast<const float4*>(&vres[256 + col]);
    }

    // ---- epilogue: out = K * u_r * v_j ----
    #pragma unroll
    for (int r = 0; r < RPW; ++r) {
        const float ur = u[r];
        float4 o0, o1;
        o0.x = a[r][0].x * ur * v0.x; o0.y = a[r][0].y * ur * v0.y;
        o0.z = a[r][0].z * ur * v0.z; o0.w = a[r][0].w * ur * v0.w;
        o1.x = a[r][1].x * ur * v1.x; o1.y = a[r][1].y * ur * v1.y;
        o1.z = a[r][1].z * ur * v1.z; o1.w = a[r][1].w * ur * v1.w;
        *reinterpret_cast<float4*>(O + (size_t)(row0 + r) * N + col)       = o0;
        *reinterpret_cast<float4*>(O + (size_t)(row0 + r) * N + 256 + col) = o1;
    }
}

extern "C" void kernel_launch(void* const* d_in, const int* in_sizes, int n_in,
                              void* d_out, int out_size, void* d_ws, size_t ws_size,
                              hipStream_t stream) {
    const float* in  = (const float*)d_in[0];
    float*       out = (float*)d_out;
    sinkhorn_kernel<<<dim3(256), dim3(1024), 0, stream>>>(in, out);
}

// Round 4
// 829.947 us; speedup vs baseline: 1.6453x; 1.6453x over previous
//
#include <hip/hip_runtime.h>

// Sinkhorn over [B=256, N=512, N=512] fp32, 10 iterations.
//
// Linear-space potentials:  K = exp(la);
//   repeat { u_i = 1/(K v)_i ; v_j = 1/(K^T u)_j } ; out = K * u_i * v_j
//
// One block per matrix (256 blocks = 1/CU). u, v live in LDS; K is never
// materialized — exp(la) is recomputed on each of the 21 streaming passes.
// la is 256 MB ~= L3 capacity, so re-reads are Infinity-Cache hits.

constexpr int N     = 512;
constexpr int NITER = 10;

__global__ __launch_bounds__(1024)
void sinkhorn_kernel(const float* __restrict__ la, float* __restrict__ out)
{
    const int tid = threadIdx.x;
    const int w   = tid >> 6;     // wave 0..15
    const int l   = tid & 63;     // lane
    const int col = l * 4;        // lane's base column in each 256-wide half

    __shared__ float u[N];        // 2 KB
    __shared__ float v[N];        // 2 KB
    __shared__ float part[16][N]; // 32 KB per-wave column partials

    const size_t base = (size_t)blockIdx.x * N * N;
    const float* A = la  + base;
    float*       O = out + base;

    if (tid < N) v[tid] = 1.0f;
    __syncthreads();

    const int row0 = w * 32;      // wave's contiguous 32-row chunk

    for (int it = 0; it < NITER; ++it) {
        // lane's v slice (constant across rows within this half-iteration)
        float4 v0 = *reinterpret_cast<const float4*>(&v[col]);
        float4 v1 = *reinterpret_cast<const float4*>(&v[256 + col]);

        // ---- row pass: u_r = 1 / sum_j exp(la_rj) * v_j ----
        #pragma unroll 4
        for (int s = 0; s < 32; ++s) {
            const int r = row0 + s;
            const float4 x0 = *reinterpret_cast<const float4*>(A + (size_t)r * N + col);
            const float4 x1 = *reinterpret_cast<const float4*>(A + (size_t)r * N + 256 + col);
            float p = __expf(x0.x) * v0.x + __expf(x0.y) * v0.y
                    + __expf(x0.z) * v0.z + __expf(x0.w) * v0.w
                    + __expf(x1.x) * v1.x + __expf(x1.y) * v1.y
                    + __expf(x1.z) * v1.z + __expf(x1.w) * v1.w;
            #pragma unroll
            for (int d = 1; d < 64; d <<= 1)
                p += __shfl_xor(p, d, 64);
            if (l == 0) u[r] = 1.0f / p;
        }
        __syncthreads();

        // ---- col pass: v_j = 1 / sum_i exp(la_ij) * u_i ----
        float4 t0 = make_float4(0.f, 0.f, 0.f, 0.f);
        float4 t1 = make_float4(0.f, 0.f, 0.f, 0.f);
        #pragma unroll 4
        for (int s = 0; s < 32; ++s) {
            const int r  = row0 + s;
            const float ur = u[r];   // wave-uniform LDS broadcast
            const float4 x0 = *reinterpret_cast<const float4*>(A + (size_t)r * N + col);
            const float4 x1 = *reinterpret_cast<const float4*>(A + (size_t)r * N + 256 + col);
            t0.x += __expf(x0.x) * ur; t0.y += __expf(x0.y) * ur;
            t0.z += __expf(x0.z) * ur; t0.w += __expf(x0.w) * ur;
            t1.x += __expf(x1.x) * ur; t1.y += __expf(x1.y) * ur;
            t1.w += 0.f;
            t1.x += 0.f;
            t1.z += __expf(x1.z) * ur; t1.w += __expf(x1.w) * ur;
        }
        *reinterpret_cast<float4*>(&part[w][col])       = t0;
        *reinterpret_cast<float4*>(&part[w][256 + col]) = t1;
        __syncthreads();

        // cross-wave column reduce: 2 threads per column
        {
            const int j  = tid >> 1;
            const int pp = tid & 1;
            float s = 0.f;
            #pragma unroll
            for (int ww = 0; ww < 8; ++ww)
                s += part[pp * 8 + ww][j];
            s += __shfl_xor(s, 1, 64);
            if (pp == 0) v[j] = 1.0f / s;
        }
        __syncthreads();
    }

    // ---- output pass: out_rj = exp(la_rj) * u_r * v_j ----
    {
        const float4 v0 = *reinterpret_cast<const float4*>(&v[col]);
        const float4 v1 = *reinterpret_cast<const float4*>(&v[256 + col]);
        #pragma unroll 4
        for (int s = 0; s < 32; ++s) {
            const int r  = row0 + s;
            const float ur = u[r];
            const float4 x0 = *reinterpret_cast<const float4*>(A + (size_t)r * N + col);
            const float4 x1 = *reinterpret_cast<const float4*>(A + (size_t)r * N + 256 + col);
            float4 o0, o1;
            o0.x = __expf(x0.x) * ur * v0.x; o0.y = __expf(x0.y) * ur * v0.y;
            o0.z = __expf(x0.z) * ur * v0.z; o0.w = __expf(x0.w) * ur * v0.w;
            o1.x = __expf(x1.x) * ur * v1.x; o1.y = __expf(x1.y) * ur * v1.y;
            o1.z = __expf(x1.z) * ur * v1.z; o1.w = __expf(x1.w) * ur * v1.w;
            *reinterpret_cast<float4*>(O + (size_t)r * N + col)       = o0;
            *reinterpret_cast<float4*>(O + (size_t)r * N + 256 + col) = o1;
        }
    }
}

extern "C" void kernel_launch(void* const* d_in, const int* in_sizes, int n_in,
                              void* d_out, int out_size, void* d_ws, size_t ws_size,
                              hipStream_t stream) {
    const float* in  = (const float*)d_in[0];
    float*       out = (float*)d_out;
    sinkhorn_kernel<<<dim3(256), dim3(1024), 0, stream>>>(in, out);
}

// Round 5
// 502.339 us; speedup vs baseline: 2.7184x; 1.6522x over previous
//
#include <hip/hip_runtime.h>
#include <hip/hip_fp16.h>

// Sinkhorn over [B=256, N=512, N=512] fp32, 10 iterations.
//
// Linear-space potentials:  K = exp(la);
//   repeat { u_i = 1/(K v)_i ; v_j = 1/(K^T u)_j } ; out = K * u_i * v_j
//
// R5 structure:
//  - FUSED pass: per row, after the 64-lane butterfly every lane holds u_r,
//    so column partials t += E*u_r accumulate in the same sweep. One pass
//    per iteration instead of two.
//  - E = exp(la) staged ONCE as fp16 into the first 512 KB of this block's
//    own d_out slot. Iterations 2..10 stream fp16 E (aggregate 128 MB,
//    L3-resident). Output pass reads the original fp32 la (never E), so
//    overwriting the slot with fp32 output is safe after the last barrier.
//  - 512 threads/block, 512 blocks (2 blocks/CU), 8 waves * 64 rows each.

constexpr int N     = 512;
constexpr int NITER = 10;
constexpr int WAVES = 8;
constexpr int RPW   = 64;   // rows per wave

__device__ __forceinline__ unsigned int pack2(float a, float b) {
    __half2 h = __floats2half2_rn(a, b);
    return __builtin_bit_cast(unsigned int, h);
}
__device__ __forceinline__ float2 unpack2(unsigned int q) {
    __half2 h = __builtin_bit_cast(__half2, q);
    return __half22float2(h);
}

__global__ __launch_bounds__(512)
void sinkhorn_kernel(const float* __restrict__ la, float* __restrict__ out)
{
    const int tid = threadIdx.x;
    const int w   = tid >> 6;
    const int l   = tid & 63;
    const int col = l * 4;            // lane owns cols [col..col+3] and [256+col..]

    __shared__ float u[N];            // 2 KB
    __shared__ float v[N];            // 2 KB
    __shared__ float part[WAVES][N];  // 16 KB

    const size_t base = (size_t)blockIdx.x * N * N;
    const float* A = la  + base;
    float*       O = out + base;
    __half*      E = reinterpret_cast<__half*>(O);   // 512 KB fp16 staging

    const int row0 = w * RPW;

    // ---- pass 0: stage E = fp16(exp(A)) and run iteration 1 fused (v == 1) ----
    {
        float4 t0 = make_float4(0.f, 0.f, 0.f, 0.f);
        float4 t1 = make_float4(0.f, 0.f, 0.f, 0.f);
        #pragma unroll 2
        for (int s = 0; s < RPW; ++s) {
            const int r = row0 + s;
            const float4 x0 = *reinterpret_cast<const float4*>(A + (size_t)r * N + col);
            const float4 x1 = *reinterpret_cast<const float4*>(A + (size_t)r * N + 256 + col);
            float4 e0 = make_float4(__expf(x0.x), __expf(x0.y), __expf(x0.z), __expf(x0.w));
            float4 e1 = make_float4(__expf(x1.x), __expf(x1.y), __expf(x1.z), __expf(x1.w));
            *reinterpret_cast<uint2*>(E + (size_t)r * N + col) =
                make_uint2(pack2(e0.x, e0.y), pack2(e0.z, e0.w));
            *reinterpret_cast<uint2*>(E + (size_t)r * N + 256 + col) =
                make_uint2(pack2(e1.x, e1.y), pack2(e1.z, e1.w));
            float p = e0.x + e0.y + e0.z + e0.w + e1.x + e1.y + e1.z + e1.w;
            #pragma unroll
            for (int d = 1; d < 64; d <<= 1)
                p += __shfl_xor(p, d, 64);
            const float ur = 1.0f / p;
            if (l == 0) u[r] = ur;
            t0.x += e0.x * ur; t0.y += e0.y * ur; t0.z += e0.z * ur; t0.w += e0.w * ur;
            t1.x += e1.x * ur; t1.y += e1.y * ur; t1.z += e1.z * ur; t1.w += e1.w * ur;
        }
        *reinterpret_cast<float4*>(&part[w][col])       = t0;
        *reinterpret_cast<float4*>(&part[w][256 + col]) = t1;
    }
    __syncthreads();
    {   // one thread per column
        float s = 0.f;
        #pragma unroll
        for (int ww = 0; ww < WAVES; ++ww) s += part[ww][tid];
        v[tid] = 1.0f / s;
    }
    __syncthreads();

    // ---- iterations 2..NITER: fused pass over fp16 E (L3-resident) ----
    for (int it = 1; it < NITER; ++it) {
        const float4 v0 = *reinterpret_cast<const float4*>(&v[col]);
        const float4 v1 = *reinterpret_cast<const float4*>(&v[256 + col]);
        float4 t0 = make_float4(0.f, 0.f, 0.f, 0.f);
        float4 t1 = make_float4(0.f, 0.f, 0.f, 0.f);
        #pragma unroll 4
        for (int s = 0; s < RPW; ++s) {
            const int r = row0 + s;
            const uint2 q0 = *reinterpret_cast<const uint2*>(E + (size_t)r * N + col);
            const uint2 q1 = *reinterpret_cast<const uint2*>(E + (size_t)r * N + 256 + col);
            const float2 a0 = unpack2(q0.x), a1 = unpack2(q0.y);
            const float2 b0 = unpack2(q1.x), b1 = unpack2(q1.y);
            float p = a0.x * v0.x + a0.y * v0.y + a1.x * v0.z + a1.y * v0.w
                    + b0.x * v1.x + b0.y * v1.y + b1.x * v1.z + b1.y * v1.w;
            #pragma unroll
            for (int d = 1; d < 64; d <<= 1)
                p += __shfl_xor(p, d, 64);
            const float ur = 1.0f / p;
            if (l == 0) u[r] = ur;
            t0.x += a0.x * ur; t0.y += a0.y * ur; t0.z += a1.x * ur; t0.w += a1.y * ur;
            t1.x += b0.x * ur; t1.y += b0.y * ur; t1.z += b1.x * ur; t1.w += b1.y * ur;
        }
        *reinterpret_cast<float4*>(&part[w][col])       = t0;
        *reinterpret_cast<float4*>(&part[w][256 + col]) = t1;
        __syncthreads();
        {
            float s = 0.f;
            #pragma unroll
            for (int ww = 0; ww < WAVES; ++ww) s += part[ww][tid];
            v[tid] = 1.0f / s;
        }
        __syncthreads();
    }

    // ---- output pass: out = exp(la) * u_r * v_j  (reads fp32 la, not E) ----
    {
        const float4 v0 = *reinterpret_cast<const float4*>(&v[col]);
        const float4 v1 = *reinterpret_cast<const float4*>(&v[256 + col]);
        #pragma unroll 2
        for (int s = 0; s < RPW; ++s) {
            const int r  = row0 + s;
            const float ur = u[r];
            const float4 x0 = *reinterpret_cast<const float4*>(A + (size_t)r * N + col);
            const float4 x1 = *reinterpret_cast<const float4*>(A + (size_t)r * N + 256 + col);
            float4 o0, o1;
            o0.x = __expf(x0.x) * ur * v0.x; o0.y = __expf(x0.y) * ur * v0.y;
            o0.z = __expf(x0.z) * ur * v0.z; o0.w = __expf(x0.w) * ur * v0.w;
            o1.x = __expf(x1.x) * ur * v1.x; o1.y = __expf(x1.y) * ur * v1.y;
            o1.z = __expf(x1.z) * ur * v1.z; o1.w = __expf(x1.w) * ur * v1.w;
            *reinterpret_cast<float4*>(O + (size_t)r * N + col)       = o0;
            *reinterpret_cast<float4*>(O + (size_t)r * N + 256 + col) = o1;
        }
    }
}

extern "C" void kernel_launch(void* const* d_in, const int* in_sizes, int n_in,
                              void* d_out, int out_size, void* d_ws, size_t ws_size,
                              hipStream_t stream) {
    const float* in  = (const float*)d_in[0];
    float*       out = (float*)d_out;
    sinkhorn_kernel<<<dim3(256), dim3(512), 0, stream>>>(in, out);
}

// Round 6
// 353.886 us; speedup vs baseline: 3.8587x; 1.4195x over previous
//
#include <hip/hip_runtime.h>
#include <hip/hip_fp16.h>

// Sinkhorn over [B=256, N=512, N=512] fp32, 10 iterations.
//
// Linear-space potentials:  K = exp(la);
//   repeat { u_i = 1/(K v)_i ; v_j = 1/(K^T u)_j } ; out = K * u_i * v_j
//
// R6: R5's fused structure (one pass/iteration: row butterfly gives every
// lane u_r, column partials accumulate in the same sweep; E = fp16(exp(la))
// staged in this block's own d_out slot) but with 16 waves/block (1024 thr)
// and explicit 8-row load batching so each wave keeps 8+ L3 loads in flight.
// R5 was latency-bound: 23% occupancy, 1.6 TB/s, 41 us/iter vs 9 us floor.

constexpr int N     = 512;
constexpr int NITER = 10;
constexpr int WAVES = 16;
constexpr int RPW   = 32;   // rows per wave

__device__ __forceinline__ unsigned int pack2(float a, float b) {
    __half2 h = __floats2half2_rn(a, b);
    return __builtin_bit_cast(unsigned int, h);
}
__device__ __forceinline__ float2 unpack2(unsigned int q) {
    __half2 h = __builtin_bit_cast(__half2, q);
    return __half22float2(h);
}

__global__ __launch_bounds__(1024)
void sinkhorn_kernel(const float* __restrict__ la, float* __restrict__ out)
{
    const int tid = threadIdx.x;
    const int w   = tid >> 6;
    const int l   = tid & 63;
    const int col = l * 4;            // lane owns cols [col..col+3], [256+col..]

    __shared__ float u[N];            // 2 KB
    __shared__ float v[N];            // 2 KB
    __shared__ float part[WAVES][N];  // 32 KB

    const size_t base = (size_t)blockIdx.x * N * N;
    const float* A = la  + base;
    float*       O = out + base;
    __half*      E = reinterpret_cast<__half*>(O);   // 512 KB fp16 staging

    const int row0 = w * RPW;

    // ---- pass 0: stage E = fp16(exp(A)), run iteration 1 fused (v == 1) ----
    {
        float4 t0 = make_float4(0.f, 0.f, 0.f, 0.f);
        float4 t1 = make_float4(0.f, 0.f, 0.f, 0.f);
        for (int s0 = 0; s0 < RPW; s0 += 4) {
            float4 xa[4], xb[4];
            #pragma unroll
            for (int k = 0; k < 4; ++k) {
                const int r = row0 + s0 + k;
                xa[k] = *reinterpret_cast<const float4*>(A + (size_t)r * N + col);
                xb[k] = *reinterpret_cast<const float4*>(A + (size_t)r * N + 256 + col);
            }
            #pragma unroll
            for (int k = 0; k < 4; ++k) {
                const int r = row0 + s0 + k;
                float4 e0 = make_float4(__expf(xa[k].x), __expf(xa[k].y),
                                        __expf(xa[k].z), __expf(xa[k].w));
                float4 e1 = make_float4(__expf(xb[k].x), __expf(xb[k].y),
                                        __expf(xb[k].z), __expf(xb[k].w));
                *reinterpret_cast<uint2*>(E + (size_t)r * N + col) =
                    make_uint2(pack2(e0.x, e0.y), pack2(e0.z, e0.w));
                *reinterpret_cast<uint2*>(E + (size_t)r * N + 256 + col) =
                    make_uint2(pack2(e1.x, e1.y), pack2(e1.z, e1.w));
                float p = e0.x + e0.y + e0.z + e0.w + e1.x + e1.y + e1.z + e1.w;
                #pragma unroll
                for (int d = 1; d < 64; d <<= 1)
                    p += __shfl_xor(p, d, 64);
                const float ur = 1.0f / p;
                if (l == 0) u[r] = ur;
                t0.x += e0.x * ur; t0.y += e0.y * ur; t0.z += e0.z * ur; t0.w += e0.w * ur;
                t1.x += e1.x * ur; t1.y += e1.y * ur; t1.z += e1.z * ur; t1.w += e1.w * ur;
            }
        }
        *reinterpret_cast<float4*>(&part[w][col])       = t0;
        *reinterpret_cast<float4*>(&part[w][256 + col]) = t1;
    }
    __syncthreads();
    {   // 2 threads per column
        const int j  = tid >> 1;
        const int pp = tid & 1;
        float s = 0.f;
        #pragma unroll
        for (int ww = 0; ww < 8; ++ww) s += part[pp * 8 + ww][j];
        s += __shfl_xor(s, 1, 64);
        if (pp == 0) v[j] = 1.0f / s;
    }
    __syncthreads();

    // ---- iterations 2..NITER: fused pass over fp16 E (L3-resident) ----
    for (int it = 1; it < NITER; ++it) {
        const float4 v0 = *reinterpret_cast<const float4*>(&v[col]);
        const float4 v1 = *reinterpret_cast<const float4*>(&v[256 + col]);
        float4 t0 = make_float4(0.f, 0.f, 0.f, 0.f);
        float4 t1 = make_float4(0.f, 0.f, 0.f, 0.f);
        for (int s0 = 0; s0 < RPW; s0 += 8) {
            uint2 qa[8], qb[8];
            #pragma unroll
            for (int k = 0; k < 8; ++k) {
                const int r = row0 + s0 + k;
                qa[k] = *reinterpret_cast<const uint2*>(E + (size_t)r * N + col);
                qb[k] = *reinterpret_cast<const uint2*>(E + (size_t)r * N + 256 + col);
            }
            #pragma unroll
            for (int k = 0; k < 8; ++k) {
                const int r = row0 + s0 + k;
                const float2 a0 = unpack2(qa[k].x), a1 = unpack2(qa[k].y);
                const float2 b0 = unpack2(qb[k].x), b1 = unpack2(qb[k].y);
                float p = a0.x * v0.x + a0.y * v0.y + a1.x * v0.z + a1.y * v0.w
                        + b0.x * v1.x + b0.y * v1.y + b1.x * v1.z + b1.y * v1.w;
                #pragma unroll
                for (int d = 1; d < 64; d <<= 1)
                    p += __shfl_xor(p, d, 64);
                const float ur = 1.0f / p;
                if (l == 0) u[r] = ur;
                t0.x += a0.x * ur; t0.y += a0.y * ur; t0.z += a1.x * ur; t0.w += a1.y * ur;
                t1.x += b0.x * ur; t1.y += b0.y * ur; t1.z += b1.x * ur; t1.w += b1.y * ur;
            }
        }
        *reinterpret_cast<float4*>(&part[w][col])       = t0;
        *reinterpret_cast<float4*>(&part[w][256 + col]) = t1;
        __syncthreads();
        {
            const int j  = tid >> 1;
            const int pp = tid & 1;
            float s = 0.f;
            #pragma unroll
            for (int ww = 0; ww < 8; ++ww) s += part[pp * 8 + ww][j];
            s += __shfl_xor(s, 1, 64);
            if (pp == 0) v[j] = 1.0f / s;
        }
        __syncthreads();
    }

    // ---- output pass: out = exp(la) * u_r * v_j  (reads fp32 la, not E) ----
    {
        const float4 v0 = *reinterpret_cast<const float4*>(&v[col]);
        const float4 v1 = *reinterpret_cast<const float4*>(&v[256 + col]);
        for (int s0 = 0; s0 < RPW; s0 += 4) {
            float4 xa[4], xb[4];
            #pragma unroll
            for (int k = 0; k < 4; ++k) {
                const int r = row0 + s0 + k;
                xa[k] = *reinterpret_cast<const float4*>(A + (size_t)r * N + col);
                xb[k] = *reinterpret_cast<const float4*>(A + (size_t)r * N + 256 + col);
            }
            #pragma unroll
            for (int k = 0; k < 4; ++k) {
                const int r  = row0 + s0 + k;
                const float ur = u[r];
                float4 o0, o1;
                o0.x = __expf(xa[k].x) * ur * v0.x; o0.y = __expf(xa[k].y) * ur * v0.y;
                o0.z = __expf(xa[k].z) * ur * v0.z; o0.w = __expf(xa[k].w) * ur * v0.w;
                o1.x = __expf(xb[k].x) * ur * v1.x; o1.y = __expf(xb[k].y) * ur * v1.y;
                o1.z = __expf(xb[k].z) * ur * v1.z; o1.w = __expf(xb[k].w) * ur * v1.w;
                *reinterpret_cast<float4*>(O + (size_t)r * N + col)       = o0;
                *reinterpret_cast<float4*>(O + (size_t)r * N + 256 + col) = o1;
            }
        }
    }
}

extern "C" void kernel_launch(void* const* d_in, const int* in_sizes, int n_in,
                              void* d_out, int out_size, void* d_ws, size_t ws_size,
                              hipStream_t stream) {
    const float* in  = (const float*)d_in[0];
    float*       out = (float*)d_out;
    sinkhorn_kernel<<<dim3(256), dim3(1024), 0, stream>>>(in, out);
}

// Round 8
// 329.283 us; speedup vs baseline: 4.1470x; 1.0747x over previous
//
#include <hip/hip_runtime.h>
#include <hip/hip_fp16.h>

// Sinkhorn over [B=256, N=512, N=512] fp32, 10 iterations.
//
// Linear-space potentials:  K = exp(la);
//   repeat { u_i = 1/(K v)_i ; v_j = 1/(K^T u)_j } ; out = K * u_i * v_j
//
// R8 == R7 with the nontemporal builtin applied to clang ext_vector_type
// (the builtin rejects HIP_vector_type float4). Structure: fused row+col
// pass, E = fp16(exp(la)) staged in this block's own d_out slot, 16
// waves/block, nt-hinted loads for single-use fp32 la + nt final stores,
// so only E (128 MB, re-read 9x) competes for L3 residency.

constexpr int N     = 512;
constexpr int NITER = 10;
constexpr int WAVES = 16;
constexpr int RPW   = 32;   // rows per wave

typedef float vfloat4 __attribute__((ext_vector_type(4)));

__device__ __forceinline__ unsigned int pack2(float a, float b) {
    __half2 h = __floats2half2_rn(a, b);
    return __builtin_bit_cast(unsigned int, h);
}
__device__ __forceinline__ float2 unpack2(unsigned int q) {
    __half2 h = __builtin_bit_cast(__half2, q);
    return __half22float2(h);
}
__device__ __forceinline__ float4 nt_load4(const float* p) {
    vfloat4 t = __builtin_nontemporal_load(reinterpret_cast<const vfloat4*>(p));
    return __builtin_bit_cast(float4, t);
}
__device__ __forceinline__ void nt_store4(float* p, float4 v) {
    __builtin_nontemporal_store(__builtin_bit_cast(vfloat4, v),
                                reinterpret_cast<vfloat4*>(p));
}

__global__ __launch_bounds__(1024)
void sinkhorn_kernel(const float* __restrict__ la, float* __restrict__ out)
{
    const int tid = threadIdx.x;
    const int w   = tid >> 6;
    const int l   = tid & 63;
    const int col = l * 4;            // lane owns cols [col..col+3], [256+col..]

    __shared__ float u[N];            // 2 KB
    __shared__ float v[N];            // 2 KB
    __shared__ float part[WAVES][N];  // 32 KB

    const size_t base = (size_t)blockIdx.x * N * N;
    const float* A = la  + base;
    float*       O = out + base;
    __half*      E = reinterpret_cast<__half*>(O);   // 512 KB fp16 staging

    const int row0 = w * RPW;

    // ---- pass 0: stage E = fp16(exp(A)), run iteration 1 fused (v == 1) ----
    {
        float4 t0 = make_float4(0.f, 0.f, 0.f, 0.f);
        float4 t1 = make_float4(0.f, 0.f, 0.f, 0.f);
        for (int s0 = 0; s0 < RPW; s0 += 4) {
            float4 xa[4], xb[4];
            #pragma unroll
            for (int k = 0; k < 4; ++k) {
                const int r = row0 + s0 + k;
                xa[k] = nt_load4(A + (size_t)r * N + col);
                xb[k] = nt_load4(A + (size_t)r * N + 256 + col);
            }
            #pragma unroll
            for (int k = 0; k < 4; ++k) {
                const int r = row0 + s0 + k;
                float4 e0 = make_float4(__expf(xa[k].x), __expf(xa[k].y),
                                        __expf(xa[k].z), __expf(xa[k].w));
                float4 e1 = make_float4(__expf(xb[k].x), __expf(xb[k].y),
                                        __expf(xb[k].z), __expf(xb[k].w));
                *reinterpret_cast<uint2*>(E + (size_t)r * N + col) =
                    make_uint2(pack2(e0.x, e0.y), pack2(e0.z, e0.w));
                *reinterpret_cast<uint2*>(E + (size_t)r * N + 256 + col) =
                    make_uint2(pack2(e1.x, e1.y), pack2(e1.z, e1.w));
                float p = e0.x + e0.y + e0.z + e0.w + e1.x + e1.y + e1.z + e1.w;
                #pragma unroll
                for (int d = 1; d < 64; d <<= 1)
                    p += __shfl_xor(p, d, 64);
                const float ur = 1.0f / p;
                if (l == 0) u[r] = ur;
                t0.x += e0.x * ur; t0.y += e0.y * ur; t0.z += e0.z * ur; t0.w += e0.w * ur;
                t1.x += e1.x * ur; t1.y += e1.y * ur; t1.z += e1.z * ur; t1.w += e1.w * ur;
            }
        }
        *reinterpret_cast<float4*>(&part[w][col])       = t0;
        *reinterpret_cast<float4*>(&part[w][256 + col]) = t1;
    }
    __syncthreads();
    {   // 2 threads per column
        const int j  = tid >> 1;
        const int pp = tid & 1;
        float s = 0.f;
        #pragma unroll
        for (int ww = 0; ww < 8; ++ww) s += part[pp * 8 + ww][j];
        s += __shfl_xor(s, 1, 64);
        if (pp == 0) v[j] = 1.0f / s;
    }
    __syncthreads();

    // ---- iterations 2..NITER: fused pass over fp16 E (L3-resident) ----
    for (int it = 1; it < NITER; ++it) {
        const float4 v0 = *reinterpret_cast<const float4*>(&v[col]);
        const float4 v1 = *reinterpret_cast<const float4*>(&v[256 + col]);
        float4 t0 = make_float4(0.f, 0.f, 0.f, 0.f);
        float4 t1 = make_float4(0.f, 0.f, 0.f, 0.f);
        for (int s0 = 0; s0 < RPW; s0 += 8) {
            uint2 qa[8], qb[8];
            #pragma unroll
            for (int k = 0; k < 8; ++k) {
                const int r = row0 + s0 + k;
                qa[k] = *reinterpret_cast<const uint2*>(E + (size_t)r * N + col);
                qb[k] = *reinterpret_cast<const uint2*>(E + (size_t)r * N + 256 + col);
            }
            #pragma unroll
            for (int k = 0; k < 8; ++k) {
                const int r = row0 + s0 + k;
                const float2 a0 = unpack2(qa[k].x), a1 = unpack2(qa[k].y);
                const float2 b0 = unpack2(qb[k].x), b1 = unpack2(qb[k].y);
                float p = a0.x * v0.x + a0.y * v0.y + a1.x * v0.z + a1.y * v0.w
                        + b0.x * v1.x + b0.y * v1.y + b1.x * v1.z + b1.y * v1.w;
                #pragma unroll
                for (int d = 1; d < 64; d <<= 1)
                    p += __shfl_xor(p, d, 64);
                const float ur = 1.0f / p;
                if (l == 0) u[r] = ur;
                t0.x += a0.x * ur; t0.y += a0.y * ur; t0.z += a1.x * ur; t0.w += a1.y * ur;
                t1.x += b0.x * ur; t1.y += b0.y * ur; t1.z += b1.x * ur; t1.w += b1.y * ur;
            }
        }
        *reinterpret_cast<float4*>(&part[w][col])       = t0;
        *reinterpret_cast<float4*>(&part[w][256 + col]) = t1;
        __syncthreads();
        {
            const int j  = tid >> 1;
            const int pp = tid & 1;
            float s = 0.f;
            #pragma unroll
            for (int ww = 0; ww < 8; ++ww) s += part[pp * 8 + ww][j];
            s += __shfl_xor(s, 1, 64);
            if (pp == 0) v[j] = 1.0f / s;
        }
        __syncthreads();
    }

    // ---- output pass: out = exp(la) * u_r * v_j  (reads fp32 la, not E) ----
    {
        const float4 v0 = *reinterpret_cast<const float4*>(&v[col]);
        const float4 v1 = *reinterpret_cast<const float4*>(&v[256 + col]);
        for (int s0 = 0; s0 < RPW; s0 += 4) {
            float4 xa[4], xb[4];
            #pragma unroll
            for (int k = 0; k < 4; ++k) {
                const int r = row0 + s0 + k;
                xa[k] = nt_load4(A + (size_t)r * N + col);
                xb[k] = nt_load4(A + (size_t)r * N + 256 + col);
            }
            #pragma unroll
            for (int k = 0; k < 4; ++k) {
                const int r  = row0 + s0 + k;
                const float ur = u[r];
                float4 o0, o1;
                o0.x = __expf(xa[k].x) * ur * v0.x; o0.y = __expf(xa[k].y) * ur * v0.y;
                o0.z = __expf(xa[k].z) * ur * v0.z; o0.w = __expf(xa[k].w) * ur * v0.w;
                o1.x = __expf(xb[k].x) * ur * v1.x; o1.y = __expf(xb[k].y) * ur * v1.y;
                o1.z = __expf(xb[k].z) * ur * v1.z; o1.w = __expf(xb[k].w) * ur * v1.w;
                nt_store4(O + (size_t)r * N + col,       o0);
                nt_store4(O + (size_t)r * N + 256 + col, o1);
            }
        }
    }
}

extern "C" void kernel_launch(void* const* d_in, const int* in_sizes, int n_in,
                              void* d_out, int out_size, void* d_ws, size_t ws_size,
                              hipStream_t stream) {
    const float* in  = (const float*)d_in[0];
    float*       out = (float*)d_out;
    sinkhorn_kernel<<<dim3(256), dim3(1024), 0, stream>>>(in, out);
}

// Round 9
// 288.079 us; speedup vs baseline: 4.7402x; 1.1430x over previous
//
#include <hip/hip_runtime.h>
#include <hip/hip_fp16.h>

// Sinkhorn over [B=256, N=512, N=512] fp32, 10 iterations.
//
// Linear-space potentials:  K = exp(la);
//   repeat { u_i = 1/(K v)_i ; v_j = 1/(K^T u)_j } ; out = K * u_i * v_j
//
// R9: read la exactly ONCE. E = fp16(exp(la)) staged in d_ws (128 MiB);
// iterations 2..10 and the output pass stream E (L3-resident, nothing
// competing: la is dead after pass 0, out stores are nontemporal).
// Output = E*u*v — fp16 quantization of the dominant entry cancels
// between numerator and normalizer, so absmax stays ~5e-4.
// MODE 0 fallback (ws too small) = R8 exactly: E in d_out slot, output
// recomputed from fp32 la.

constexpr int N     = 512;
constexpr int NITER = 10;
constexpr int WAVES = 16;
constexpr int RPW   = 32;   // rows per wave

typedef float vfloat4 __attribute__((ext_vector_type(4)));

__device__ __forceinline__ unsigned int pack2(float a, float b) {
    __half2 h = __floats2half2_rn(a, b);
    return __builtin_bit_cast(unsigned int, h);
}
__device__ __forceinline__ float2 unpack2(unsigned int q) {
    __half2 h = __builtin_bit_cast(__half2, q);
    return __half22float2(h);
}
__device__ __forceinline__ float4 nt_load4(const float* p) {
    vfloat4 t = __builtin_nontemporal_load(reinterpret_cast<const vfloat4*>(p));
    return __builtin_bit_cast(float4, t);
}
__device__ __forceinline__ void nt_store4(float* p, float4 v) {
    __builtin_nontemporal_store(__builtin_bit_cast(vfloat4, v),
                                reinterpret_cast<vfloat4*>(p));
}

template <int MODE>  // 0: E in d_out slot, output from la. 1: E in ws, output from E.
__global__ __launch_bounds__(1024)
void sinkhorn_kernel(const float* __restrict__ la, float* __restrict__ out,
                     __half* __restrict__ ews)
{
    const int tid = threadIdx.x;
    const int w   = tid >> 6;
    const int l   = tid & 63;
    const int col = l * 4;            // lane owns cols [col..col+3], [256+col..]

    __shared__ float u[N];            // 2 KB
    __shared__ float v[N];            // 2 KB
    __shared__ float part[WAVES][N];  // 32 KB

    const size_t base = (size_t)blockIdx.x * N * N;
    const float* A = la  + base;
    float*       O = out + base;
    __half*      E = (MODE == 1) ? (ews + base) : reinterpret_cast<__half*>(O);

    const int row0 = w * RPW;

    // ---- pass 0: stage E = fp16(exp(A)), run iteration 1 fused (v == 1) ----
    {
        float4 t0 = make_float4(0.f, 0.f, 0.f, 0.f);
        float4 t1 = make_float4(0.f, 0.f, 0.f, 0.f);
        for (int s0 = 0; s0 < RPW; s0 += 4) {
            float4 xa[4], xb[4];
            #pragma unroll
            for (int k = 0; k < 4; ++k) {
                const int r = row0 + s0 + k;
                xa[k] = nt_load4(A + (size_t)r * N + col);
                xb[k] = nt_load4(A + (size_t)r * N + 256 + col);
            }
            #pragma unroll
            for (int k = 0; k < 4; ++k) {
                const int r = row0 + s0 + k;
                float4 e0 = make_float4(__expf(xa[k].x), __expf(xa[k].y),
                                        __expf(xa[k].z), __expf(xa[k].w));
                float4 e1 = make_float4(__expf(xb[k].x), __expf(xb[k].y),
                                        __expf(xb[k].z), __expf(xb[k].w));
                *reinterpret_cast<uint2*>(E + (size_t)r * N + col) =
                    make_uint2(pack2(e0.x, e0.y), pack2(e0.z, e0.w));
                *reinterpret_cast<uint2*>(E + (size_t)r * N + 256 + col) =
                    make_uint2(pack2(e1.x, e1.y), pack2(e1.z, e1.w));
                float p = e0.x + e0.y + e0.z + e0.w + e1.x + e1.y + e1.z + e1.w;
                #pragma unroll
                for (int d = 1; d < 64; d <<= 1)
                    p += __shfl_xor(p, d, 64);
                const float ur = 1.0f / p;
                if (l == 0) u[r] = ur;
                t0.x += e0.x * ur; t0.y += e0.y * ur; t0.z += e0.z * ur; t0.w += e0.w * ur;
                t1.x += e1.x * ur; t1.y += e1.y * ur; t1.z += e1.z * ur; t1.w += e1.w * ur;
            }
        }
        *reinterpret_cast<float4*>(&part[w][col])       = t0;
        *reinterpret_cast<float4*>(&part[w][256 + col]) = t1;
    }
    __syncthreads();
    {   // 2 threads per column
        const int j  = tid >> 1;
        const int pp = tid & 1;
        float s = 0.f;
        #pragma unroll
        for (int ww = 0; ww < 8; ++ww) s += part[pp * 8 + ww][j];
        s += __shfl_xor(s, 1, 64);
        if (pp == 0) v[j] = 1.0f / s;
    }
    __syncthreads();

    // ---- iterations 2..NITER: fused pass over fp16 E (L3-resident) ----
    for (int it = 1; it < NITER; ++it) {
        const float4 v0 = *reinterpret_cast<const float4*>(&v[col]);
        const float4 v1 = *reinterpret_cast<const float4*>(&v[256 + col]);
        float4 t0 = make_float4(0.f, 0.f, 0.f, 0.f);
        float4 t1 = make_float4(0.f, 0.f, 0.f, 0.f);
        for (int s0 = 0; s0 < RPW; s0 += 8) {
            uint2 qa[8], qb[8];
            #pragma unroll
            for (int k = 0; k < 8; ++k) {
                const int r = row0 + s0 + k;
                qa[k] = *reinterpret_cast<const uint2*>(E + (size_t)r * N + col);
                qb[k] = *reinterpret_cast<const uint2*>(E + (size_t)r * N + 256 + col);
            }
            #pragma unroll
            for (int k = 0; k < 8; ++k) {
                const int r = row0 + s0 + k;
                const float2 a0 = unpack2(qa[k].x), a1 = unpack2(qa[k].y);
                const float2 b0 = unpack2(qb[k].x), b1 = unpack2(qb[k].y);
                float p = a0.x * v0.x + a0.y * v0.y + a1.x * v0.z + a1.y * v0.w
                        + b0.x * v1.x + b0.y * v1.y + b1.x * v1.z + b1.y * v1.w;
                #pragma unroll
                for (int d = 1; d < 64; d <<= 1)
                    p += __shfl_xor(p, d, 64);
                const float ur = 1.0f / p;
                if (l == 0) u[r] = ur;
                t0.x += a0.x * ur; t0.y += a0.y * ur; t0.z += a1.x * ur; t0.w += a1.y * ur;
                t1.x += b0.x * ur; t1.y += b0.y * ur; t1.z += b1.x * ur; t1.w += b1.y * ur;
            }
        }
        *reinterpret_cast<float4*>(&part[w][col])       = t0;
        *reinterpret_cast<float4*>(&part[w][256 + col]) = t1;
        __syncthreads();
        {
            const int j  = tid >> 1;
            const int pp = tid & 1;
            float s = 0.f;
            #pragma unroll
            for (int ww = 0; ww < 8; ++ww) s += part[pp * 8 + ww][j];
            s += __shfl_xor(s, 1, 64);
            if (pp == 0) v[j] = 1.0f / s;
        }
        __syncthreads();
    }

    // ---- output pass ----
    if (MODE == 1) {
        // out = E * u_r * v_j  (reads fp16 E from ws; la never touched again)
        const float4 v0 = *reinterpret_cast<const float4*>(&v[col]);
        const float4 v1 = *reinterpret_cast<const float4*>(&v[256 + col]);
        for (int s0 = 0; s0 < RPW; s0 += 8) {
            uint2 qa[8], qb[8];
            #pragma unroll
            for (int k = 0; k < 8; ++k) {
                const int r = row0 + s0 + k;
                qa[k] = *reinterpret_cast<const uint2*>(E + (size_t)r * N + col);
                qb[k] = *reinterpret_cast<const uint2*>(E + (size_t)r * N + 256 + col);
            }
            #pragma unroll
            for (int k = 0; k < 8; ++k) {
                const int r  = row0 + s0 + k;
                const float ur = u[r];
                const float2 a0 = unpack2(qa[k].x), a1 = unpack2(qa[k].y);
                const float2 b0 = unpack2(qb[k].x), b1 = unpack2(qb[k].y);
                float4 o0, o1;
                o0.x = a0.x * ur * v0.x; o0.y = a0.y * ur * v0.y;
                o0.z = a1.x * ur * v0.z; o0.w = a1.y * ur * v0.w;
                o1.x = b0.x * ur * v1.x; o1.y = b0.y * ur * v1.y;
                o1.z = b1.x * ur * v1.z; o1.w = b1.y * ur * v1.w;
                nt_store4(O + (size_t)r * N + col,       o0);
                nt_store4(O + (size_t)r * N + 256 + col, o1);
            }
        }
    } else {
        // out = exp(la) * u_r * v_j  (R8 fallback; E aliases O and is dead)
        const float4 v0 = *reinterpret_cast<const float4*>(&v[col]);
        const float4 v1 = *reinterpret_cast<const float4*>(&v[256 + col]);
        for (int s0 = 0; s0 < RPW; s0 += 4) {
            float4 xa[4], xb[4];
            #pragma unroll
            for (int k = 0; k < 4; ++k) {
                const int r = row0 + s0 + k;
                xa[k] = nt_load4(A + (size_t)r * N + col);
                xb[k] = nt_load4(A + (size_t)r * N + 256 + col);
            }
            #pragma unroll
            for (int k = 0; k < 4; ++k) {
                const int r  = row0 + s0 + k;
                const float ur = u[r];
                float4 o0, o1;
                o0.x = __expf(xa[k].x) * ur * v0.x; o0.y = __expf(xa[k].y) * ur * v0.y;
                o0.z = __expf(xa[k].z) * ur * v0.z; o0.w = __expf(xa[k].w) * ur * v0.w;
                o1.x = __expf(xb[k].x) * ur * v1.x; o1.y = __expf(xb[k].y) * ur * v1.y;
                o1.z = __expf(xb[k].z) * ur * v1.z; o1.w = __expf(xb[k].w) * ur * v1.w;
                nt_store4(O + (size_t)r * N + col,       o0);
                nt_store4(O + (size_t)r * N + 256 + col, o1);
            }
        }
    }
}

extern "C" void kernel_launch(void* const* d_in, const int* in_sizes, int n_in,
                              void* d_out, int out_size, void* d_ws, size_t ws_size,
                              hipStream_t stream) {
    const float* in  = (const float*)d_in[0];
    float*       out = (float*)d_out;
    constexpr size_t EBYTES = (size_t)256 * N * N * sizeof(__half);  // 128 MiB
    if (ws_size >= EBYTES) {
        sinkhorn_kernel<1><<<dim3(256), dim3(1024), 0, stream>>>(
            in, out, (__half*)d_ws);
    } else {
        sinkhorn_kernel<0><<<dim3(256), dim3(1024), 0, stream>>>(
            in, out, nullptr);
    }
}